// Round 6
// baseline (2018.242 us; speedup 1.0000x reference)
//
#include <hip/hip_runtime.h>
#include <hip/hip_bf16.h>
#include <hip/hip_cooperative_groups.h>
#include <cstddef>
#include <cstdint>

// RNN-T decode fused pipeline. fp32 pipeline + bf16-MFMA joint GEMM (fused A).
// Shapes: B=4, T=256, U+1=65, ENC_D=512, H=PRED_H=640, J=640, V+1=1025.
// Output: [B, T, U+1, V+1] fp32 = 68,224,000 elements.

#define BB 4
#define TT 256
#define U1 65
#define HH 640
#define G4 2560   // 4*H
#define ED 512
#define JJ 640
#define V1 1025
#define MROWS (BB*TT*U1)   // 66560

typedef __attribute__((ext_vector_type(8))) short bf16x8;
typedef __attribute__((ext_vector_type(4))) float f32x4;

#define GLOAD_LDS16(g, s) __builtin_amdgcn_global_load_lds( \
    (const __attribute__((address_space(1))) void*)(g), \
    (__attribute__((address_space(3))) void*)(s), 16, 0, 0)

__device__ __forceinline__ float sigm(float x) { return 1.f / (1.f + expf(-x)); }

// ---------------- tiled transpose: in[R][C] -> out[C][R], R,C multiples of 32 ----
__global__ __launch_bounds__(256) void transpose_tiled(const float* __restrict__ in,
                                                       float* __restrict__ out,
                                                       int R, int C) {
    __shared__ float t[32][33];
    const int bx = blockIdx.x * 32;   // c-base
    const int by = blockIdx.y * 32;   // r-base
    const int x = threadIdx.x & 31;
    const int y0 = threadIdx.x >> 5;  // 0..7
#pragma unroll
    for (int i = 0; i < 32; i += 8)
        t[y0 + i][x] = in[(size_t)(by + y0 + i) * C + bx + x];
    __syncthreads();
#pragma unroll
    for (int i = 0; i < 32; i += 8)
        out[(size_t)(bx + y0 + i) * R + by + x] = t[x][y0 + i];
}

// ---------------- build y: [260][640], row=(b,u); u==0 -> 0 else embed[targets[b][u-1]]
__global__ __launch_bounds__(256) void build_y(const int* __restrict__ tgt,
                                               const float* __restrict__ embed,
                                               float* __restrict__ y) {
    int idx = blockIdx.x * 256 + threadIdx.x;
    if (idx >= BB * U1 * HH) return;
    int h = idx % HH;
    int bu = idx / HH;
    int u = bu % U1, b = bu / U1;
    y[idx] = (u == 0) ? 0.f : embed[(size_t)tgt[b * 64 + (u - 1)] * HH + h];
}

// ---------------- X = y @ w_ih.T + b_ih + b_hh : [260][2560] ----------------
__global__ __launch_bounds__(256) void gemm_x(const float* __restrict__ y,
                                              const float* __restrict__ w_ihT,
                                              const float* __restrict__ b_ih,
                                              const float* __restrict__ b_hh,
                                              float* __restrict__ X) {
    __shared__ float ys[4][HH];
    int cg = blockIdx.x % 10;
    int rg = blockIdx.x / 10;
    int row = cg * 256 + threadIdx.x;   // gate-row 0..2559
    for (int e = threadIdx.x; e < 4 * HH / 4; e += 256)
        ((float4*)ys)[e] = ((const float4*)(y + (size_t)rg * 4 * HH))[e];
    __syncthreads();
    float bias = b_ih[row] + b_hh[row];
    float a0 = bias, a1 = bias, a2 = bias, a3 = bias;
#pragma unroll 8
    for (int k = 0; k < HH; k++) {
        float w = w_ihT[(size_t)k * G4 + row];
        a0 += ys[0][k] * w;
        a1 += ys[1][k] * w;
        a2 += ys[2][k] * w;
        a3 += ys[3][k] * w;
    }
    X[(size_t)(rg * 4 + 0) * G4 + row] = a0;
    X[(size_t)(rg * 4 + 1) * G4 + row] = a1;
    X[(size_t)(rg * 4 + 2) * G4 + row] = a2;
    X[(size_t)(rg * 4 + 3) * G4 + row] = a3;
}

// ---------------- whole LSTM in one cooperative kernel ----------------
// grid = 80 blocks (4 batches x 20 chunks of 32 hidden units), 256 threads.
// Thread map per step: (row-quad q 0..31, k-slice ksl 0..7). Each thread does an
// 80-k float4 GEMV strip (w_hhT float4 loads, wave = contiguous 512B per k),
// 8-way LDS reduction, pointwise by threads 0..31 (c-state in registers),
// grid.sync per step. Block's w_hhT slice (327KB) stays L2-resident on its XCD.
// X is prefetched per step before the GEMV (h-independent) to hide its latency.
__global__ __launch_bounds__(256) void lstm_all(const float* __restrict__ X,
                                                const float* __restrict__ w_hhT,
                                                float* __restrict__ pred) {
    int b = blockIdx.x / 20;
    int chunk = blockIdx.x % 20;
    __shared__ float hs[HH];
    __shared__ float part[8][128];
    __shared__ float gl[128];
    const int tid = threadIdx.x;
    const int q = tid & 31;           // row-quad 0..31 (4 consecutive gate-rows)
    const int ksl = tid >> 5;         // k-slice 0..7 (80 k each)
    const int g = q >> 3, jq = q & 7;
    const int grow = g * HH + chunk * 32 + jq * 4;   // global gate-row of quad base
    const float4* w4 = (const float4*)w_hhT;         // [k][G4/4]
    const int w4idx0 = grow >> 2;
    const int rowX = (tid >> 5) * HH + chunk * 32 + (tid & 31);  // for tid<128
    float creg = 0.f;                 // c state (threads 0..31)
    cooperative_groups::grid_group grid = cooperative_groups::this_grid();

    for (int s = 0; s < U1; s++) {
        float xv = 0.f;
        if (tid < 128) xv = X[(size_t)(b * U1 + s) * G4 + rowX];   // early issue
        if (tid < 160) {
            ((float4*)hs)[tid] = (s == 0) ? (float4){0.f, 0.f, 0.f, 0.f}
                : ((const float4*)(pred + (size_t)(b * U1 + (s - 1)) * HH))[tid];
        }
        __syncthreads();
        float4 acc = {0.f, 0.f, 0.f, 0.f};
        const int k0 = ksl * 80;
#pragma unroll 8
        for (int k = 0; k < 80; k++) {
            float h = hs[k0 + k];
            float4 w = w4[(size_t)(k0 + k) * (G4 / 4) + w4idx0];
            acc.x += h * w.x; acc.y += h * w.y; acc.z += h * w.z; acc.w += h * w.w;
        }
        *(float4*)&part[ksl][q * 4] = acc;
        __syncthreads();
        if (tid < 128) {
            float sum = 0.f;
#pragma unroll
            for (int i = 0; i < 8; i++) sum += part[i][tid];
            gl[tid] = sum + xv;
        }
        __syncthreads();
        if (tid < 32) {
            float iv = sigm(gl[0 * 32 + tid]);
            float fv = sigm(gl[1 * 32 + tid]);
            float gv = tanhf(gl[2 * 32 + tid]);
            float ov = sigm(gl[3 * 32 + tid]);
            creg = fv * creg + iv * gv;
            float h = ov * tanhf(creg);
            pred[(size_t)(b * U1 + s) * HH + chunk * 32 + tid] = h;
        }
        grid.sync();
    }
}

// ---------------- f_enc = encT @ enc_w.T + enc_b : [1024][640] ----------------
__global__ __launch_bounds__(256) void fenc_k(const float* __restrict__ encT,
                                              const float* __restrict__ enc_wT,
                                              const float* __restrict__ enc_b,
                                              float* __restrict__ fenc) {
    __shared__ float es[4][ED];
    int r0 = blockIdx.x * 4;   // (b,t) flat
    for (int e = threadIdx.x; e < 4 * ED / 4; e += 256)
        ((float4*)es)[e] = ((const float4*)(encT + (size_t)r0 * ED))[e];
    __syncthreads();
    for (int j = threadIdx.x; j < JJ; j += 256) {
        float bias = enc_b[j];
        float a0 = bias, a1 = bias, a2 = bias, a3 = bias;
#pragma unroll 8
        for (int d = 0; d < ED; d++) {
            float w = enc_wT[(size_t)d * JJ + j];
            a0 += es[0][d] * w;
            a1 += es[1][d] * w;
            a2 += es[2][d] * w;
            a3 += es[3][d] * w;
        }
        fenc[(size_t)(r0 + 0) * JJ + j] = a0;
        fenc[(size_t)(r0 + 1) * JJ + j] = a1;
        fenc[(size_t)(r0 + 2) * JJ + j] = a2;
        fenc[(size_t)(r0 + 3) * JJ + j] = a3;
    }
}

// ---------------- f_pred = pred @ pred_w.T + pred_b : [260][640] ----------------
__global__ __launch_bounds__(256) void fpred_k(const float* __restrict__ pred,
                                               const float* __restrict__ pred_wT,
                                               const float* __restrict__ pred_b,
                                               float* __restrict__ fpred) {
    __shared__ float ps[4][HH];
    int r0 = blockIdx.x * 4;   // (b,u) flat
    for (int e = threadIdx.x; e < 4 * HH / 4; e += 256)
        ((float4*)ps)[e] = ((const float4*)(pred + (size_t)r0 * HH))[e];
    __syncthreads();
    for (int j = threadIdx.x; j < JJ; j += 256) {
        float bias = pred_b[j];
        float a0 = bias, a1 = bias, a2 = bias, a3 = bias;
#pragma unroll 8
        for (int k = 0; k < HH; k++) {
            float w = pred_wT[(size_t)k * JJ + j];
            a0 += ps[0][k] * w;
            a1 += ps[1][k] * w;
            a2 += ps[2][k] * w;
            a3 += ps[3][k] * w;
        }
        fpred[(size_t)(r0 + 0) * JJ + j] = a0;
        fpred[(size_t)(r0 + 1) * JJ + j] = a1;
        fpred[(size_t)(r0 + 2) * JJ + j] = a2;
        fpred[(size_t)(r0 + 3) * JJ + j] = a3;
    }
}

// ---------------- convert fp32 -> bf16 (for out_w), vectorized ----------------
__global__ __launch_bounds__(256) void cvt_bf16_k(const float4* __restrict__ in,
                                                  ushort4* __restrict__ outp, int n4) {
    int i = blockIdx.x * 256 + threadIdx.x;
    if (i >= n4) return;
    float4 v = in[i];
    ushort4 o;
    __hip_bfloat16 h0 = __float2bfloat16(v.x);
    __hip_bfloat16 h1 = __float2bfloat16(v.y);
    __hip_bfloat16 h2 = __float2bfloat16(v.z);
    __hip_bfloat16 h3 = __float2bfloat16(v.w);
    o.x = *(ushort*)&h0; o.y = *(ushort*)&h1;
    o.z = *(ushort*)&h2; o.w = *(ushort*)&h3;
    outp[i] = o;
}

// ---------------- joint GEMM (bf16 MFMA, m97-style, fused A) ----------------
// C[m][v] = sum_k relu(fenc[bt][k]+fpred[b,u][k]) * W[v][k] + out_b[v]
// m = bt*65+u in [0,66560), v in [0,1025). tile 128x128, BK=32, 4 waves.
// A-tile reg-staged from fenc/fpred (L2-hot) + ds_write; W via global_load_lds(16B).
// grid = dim3(9, 520) with XCD-grouping swizzle (4680 % 8 == 0 -> bijective):
// all 9 n-tiles of an m-row land on one XCD -> A-side reads hit that XCD's L2.
__global__ __launch_bounds__(256) void joint_mfma(const float* __restrict__ fenc,
                                                  const float* __restrict__ fpred,
                                                  const __hip_bfloat16* __restrict__ W,
                                                  const float* __restrict__ out_b,
                                                  float* __restrict__ out) {
    __shared__ __align__(16) short Abuf[2][4096];   // [128 m][32 k] bf16, 64B rows
    __shared__ __align__(16) short Bbuf[2][4096];   // [128 v][32 k] bf16
    const int lin = blockIdx.y * 9 + blockIdx.x;
    const int swz = (lin & 7) * 585 + (lin >> 3);
    const int v0 = (swz % 9) * 128;
    const int row0 = (swz / 9) * 128;
    const int tid = threadIdx.x;
    const int l = tid & 63;
    const int wv = tid >> 6;          // wave 0..3
    const int wr = wv >> 1, wc = wv & 1;

    // ---- W staging (global_load_lds): wave wv covers v-rows [wv*32, wv*32+32)
    const char* Wb = (const char*)W;
    const int brow = v0 + wv * 32 + (l >> 2);
    const int ksegB = (l & 3) * 16;

    // ---- A staging (reg): thread t -> m-row t>>1, k-half t&1 (16 k's)
    const int arow_l = tid >> 1;
    const int kh = tid & 1;
    const int am = row0 + arow_l;
    const int abt = am / 65;
    const int au = am - abt * 65;
    const int ab = abt >> 8;
    const float* feP = fenc + (size_t)abt * JJ + kh * 16;
    const float* fpP = fpred + (size_t)(ab * U1 + au) * JJ + kh * 16;

    f32x4 acc[4][4];
#pragma unroll
    for (int i = 0; i < 4; i++)
#pragma unroll
        for (int j = 0; j < 4; j++) acc[i][j] = (f32x4){0.f, 0.f, 0.f, 0.f};

    auto stageW = [&](int buf, int kc) {
        size_t kb = (size_t)kc * 64;   // 32 bf16 = 64B per v-row chunk
#pragma unroll
        for (int i = 0; i < 2; i++) {
            int vr = brow + i * 16;
            if (vr > 1024) vr = 1024;   // padded n-tile: clamp to a valid row
            const char* g = Wb + (size_t)vr * 1280 + kb + ksegB;
            GLOAD_LDS16(g, &Bbuf[buf][wv * 1024 + i * 512]);
        }
    };
    auto stageA = [&](int buf, int kc) {
        const int k0 = kc * 32;
        float4 e0 = *(const float4*)(feP + k0);
        float4 e1 = *(const float4*)(feP + k0 + 4);
        float4 e2 = *(const float4*)(feP + k0 + 8);
        float4 e3 = *(const float4*)(feP + k0 + 12);
        float4 p0 = *(const float4*)(fpP + k0);
        float4 p1 = *(const float4*)(fpP + k0 + 4);
        float4 p2 = *(const float4*)(fpP + k0 + 8);
        float4 p3 = *(const float4*)(fpP + k0 + 12);
        float v[16] = {
            e0.x + p0.x, e0.y + p0.y, e0.z + p0.z, e0.w + p0.w,
            e1.x + p1.x, e1.y + p1.y, e1.z + p1.z, e1.w + p1.w,
            e2.x + p2.x, e2.y + p2.y, e2.z + p2.z, e2.w + p2.w,
            e3.x + p3.x, e3.y + p3.y, e3.z + p3.z, e3.w + p3.w};
        union { ushort h[16]; uint4 q[2]; } pk;
#pragma unroll
        for (int i = 0; i < 16; i++) {
            __hip_bfloat16 hb = __float2bfloat16(fmaxf(v[i], 0.f));
            pk.h[i] = *(ushort*)&hb;
        }
        *(uint4*)&Abuf[buf][arow_l * 32 + kh * 16] = pk.q[0];
        *(uint4*)&Abuf[buf][arow_l * 32 + kh * 16 + 8] = pk.q[1];
    };

    stageW(0, 0);
    stageA(0, 0);
    int cur = 0;
    const int lr = l & 15, lg = l >> 4;
    for (int kc = 0; kc < 20; kc++) {
        __syncthreads();               // drains vmcnt (gload_lds) + lgkmcnt (ds_write)
        if (kc < 19) stageW(cur ^ 1, kc + 1);
        bf16x8 af[4], bfr[4];
#pragma unroll
        for (int mf = 0; mf < 4; mf++)
            af[mf] = *(const bf16x8*)&Abuf[cur][(wr * 64 + mf * 16 + lr) * 32 + lg * 8];
#pragma unroll
        for (int nf = 0; nf < 4; nf++)
            bfr[nf] = *(const bf16x8*)&Bbuf[cur][(wc * 64 + nf * 16 + lr) * 32 + lg * 8];
#pragma unroll
        for (int mf = 0; mf < 4; mf++)
#pragma unroll
            for (int nf = 0; nf < 4; nf++)
                acc[mf][nf] = __builtin_amdgcn_mfma_f32_16x16x32_bf16(af[mf], bfr[nf], acc[mf][nf], 0, 0, 0);
        if (kc < 19) stageA(cur ^ 1, kc + 1);   // global loads hoist above MFMAs; cvt+ds_write after
        cur ^= 1;
    }

    // epilogue: C/D layout col=lane&15, row=(lane>>4)*4+reg
#pragma unroll
    for (int nf = 0; nf < 4; nf++) {
        int vcol = v0 + wc * 64 + nf * 16 + lr;
        if (vcol < V1) {
            float bias = out_b[vcol];
#pragma unroll
            for (int mf = 0; mf < 4; mf++) {
#pragma unroll
                for (int rg = 0; rg < 4; rg++) {
                    int m = row0 + wr * 64 + mf * 16 + lg * 4 + rg;
                    out[(size_t)m * V1 + vcol] = acc[mf][nf][rg] + bias;
                }
            }
        }
    }
}

extern "C" void kernel_launch(void* const* d_in, const int* in_sizes, int n_in,
                              void* d_out, int out_size, void* d_ws, size_t ws_size,
                              hipStream_t stream) {
    const float* enc = (const float*)d_in[0];
    const int* targets = (const int*)d_in[2];
    const float* embed = (const float*)d_in[4];
    const float* w_ih = (const float*)d_in[5];
    const float* w_hh = (const float*)d_in[6];
    const float* b_ih = (const float*)d_in[7];
    const float* b_hh = (const float*)d_in[8];
    const float* enc_w = (const float*)d_in[9];
    const float* enc_b = (const float*)d_in[10];
    const float* pred_w = (const float*)d_in[11];
    const float* pred_b = (const float*)d_in[12];
    const float* out_w = (const float*)d_in[13];
    const float* out_b = (const float*)d_in[14];
    float* out = (float*)d_out;

    float* w0 = (float*)d_ws;
    size_t o = 0;
    float* w_ihT = w0 + o; o += (size_t)640 * 2560;   // [k][gate-row]
    float* w_hhT = w0 + o; o += (size_t)640 * 2560;
    float* enc_wT = w0 + o; o += (size_t)512 * 640;   // [d][j]
    float* pred_wT = w0 + o; o += (size_t)640 * 640;  // [k][j]
    float* encT = w0 + o; o += (size_t)BB * TT * ED;  // [b][t][d]
    float* y = w0 + o; o += (size_t)BB * U1 * HH;
    float* X = w0 + o; o += (size_t)BB * U1 * G4;
    float* pred = w0 + o; o += (size_t)BB * U1 * HH;
    float* fenc = w0 + o; o += (size_t)BB * TT * JJ;
    float* fpred = w0 + o; o += (size_t)BB * U1 * JJ;
    __hip_bfloat16* W_bf = (__hip_bfloat16*)(w0 + o); o += (size_t)V1 * JJ / 2 + 8;

    auto TP = [&](const float* in, float* outp, int R, int C) {
        transpose_tiled<<<dim3(C / 32, R / 32), 256, 0, stream>>>(in, outp, R, C);
    };
    TP(w_ih, w_ihT, 2560, 640);
    TP(w_hh, w_hhT, 2560, 640);
    TP(enc_w, enc_wT, 640, 512);
    TP(pred_w, pred_wT, 640, 640);
    for (int b = 0; b < BB; b++)
        TP(enc + (size_t)b * ED * TT, encT + (size_t)b * TT * ED, ED, TT);

    build_y<<<(BB * U1 * HH + 255) / 256, 256, 0, stream>>>(targets, embed, y);
    gemm_x<<<650, 256, 0, stream>>>(y, w_ihT, b_ih, b_hh, X);

    {
        void* kargs[] = {(void*)&X, (void*)&w_hhT, (void*)&pred};
        hipLaunchCooperativeKernel((void*)lstm_all, dim3(80), dim3(256), kargs, 0, stream);
    }

    fenc_k<<<BB * TT / 4, 256, 0, stream>>>(encT, enc_wT, enc_b, fenc);
    fpred_k<<<BB * U1 / 4, 256, 0, stream>>>(pred, pred_wT, pred_b, fpred);
    cvt_bf16_k<<<(V1 * JJ / 4 + 255) / 256, 256, 0, stream>>>((const float4*)out_w,
                                                              (ushort4*)W_bf, V1 * JJ / 4);
    joint_mfma<<<dim3(9, 520), 256, 0, stream>>>(fenc, fpred, W_bf, out_b, out);
}

// Round 8
// 1636.770 us; speedup vs baseline: 1.2331x; 1.2331x over previous
//
#include <hip/hip_runtime.h>
#include <hip/hip_bf16.h>
#include <hip/hip_cooperative_groups.h>
#include <cstddef>
#include <cstdint>

// RNN-T decode fused pipeline. fp32 pipeline + bf16-MFMA joint GEMM (fused A).
// Shapes: B=4, T=256, U+1=65, ENC_D=512, H=PRED_H=640, J=640, V+1=1025.
// Output: [B, T, U+1, V+1] fp32 = 68,224,000 elements.

#define BB 4
#define TT 256
#define U1 65
#define HH 640
#define G4 2560   // 4*H
#define ED 512
#define JJ 640
#define V1 1025
#define MROWS (BB*TT*U1)   // 66560

typedef __attribute__((ext_vector_type(8))) short bf16x8;
typedef __attribute__((ext_vector_type(4))) float f32x4;

#define GLOAD_LDS16(g, s) __builtin_amdgcn_global_load_lds( \
    (const __attribute__((address_space(1))) void*)(g), \
    (__attribute__((address_space(3))) void*)(s), 16, 0, 0)

__device__ __forceinline__ float sigm(float x) { return 1.f / (1.f + expf(-x)); }

// ---------------- tiled transpose: in[R][C] -> out[C][R], R,C multiples of 32 ----
__global__ __launch_bounds__(256) void transpose_tiled(const float* __restrict__ in,
                                                       float* __restrict__ out,
                                                       int R, int C) {
    __shared__ float t[32][33];
    const int bx = blockIdx.x * 32;   // c-base
    const int by = blockIdx.y * 32;   // r-base
    const int x = threadIdx.x & 31;
    const int y0 = threadIdx.x >> 5;  // 0..7
#pragma unroll
    for (int i = 0; i < 32; i += 8)
        t[y0 + i][x] = in[(size_t)(by + y0 + i) * C + bx + x];
    __syncthreads();
#pragma unroll
    for (int i = 0; i < 32; i += 8)
        out[(size_t)(bx + y0 + i) * R + by + x] = t[x][y0 + i];
}

// ---------------- zero the barrier counters (ws is poisoned every call) -------
__global__ __launch_bounds__(256) void zero_cnt(int* __restrict__ cnt) {
    int i = blockIdx.x * 256 + threadIdx.x;
    if (i < BB * U1) cnt[i] = 0;
}

// ---------------- build y: [260][640], row=(b,u); u==0 -> 0 else embed[targets[b][u-1]]
__global__ __launch_bounds__(256) void build_y(const int* __restrict__ tgt,
                                               const float* __restrict__ embed,
                                               float* __restrict__ y) {
    int idx = blockIdx.x * 256 + threadIdx.x;
    if (idx >= BB * U1 * HH) return;
    int h = idx % HH;
    int bu = idx / HH;
    int u = bu % U1, b = bu / U1;
    y[idx] = (u == 0) ? 0.f : embed[(size_t)tgt[b * 64 + (u - 1)] * HH + h];
}

// ---------------- X = y @ w_ih.T + b_ih + b_hh : [260][2560] ----------------
__global__ __launch_bounds__(256) void gemm_x(const float* __restrict__ y,
                                              const float* __restrict__ w_ihT,
                                              const float* __restrict__ b_ih,
                                              const float* __restrict__ b_hh,
                                              float* __restrict__ X) {
    __shared__ float ys[4][HH];
    int cg = blockIdx.x % 10;
    int rg = blockIdx.x / 10;
    int row = cg * 256 + threadIdx.x;   // gate-row 0..2559
    for (int e = threadIdx.x; e < 4 * HH / 4; e += 256)
        ((float4*)ys)[e] = ((const float4*)(y + (size_t)rg * 4 * HH))[e];
    __syncthreads();
    float bias = b_ih[row] + b_hh[row];
    float a0 = bias, a1 = bias, a2 = bias, a3 = bias;
#pragma unroll 8
    for (int k = 0; k < HH; k++) {
        float w = w_ihT[(size_t)k * G4 + row];
        a0 += ys[0][k] * w;
        a1 += ys[1][k] * w;
        a2 += ys[2][k] * w;
        a3 += ys[3][k] * w;
    }
    X[(size_t)(rg * 4 + 0) * G4 + row] = a0;
    X[(size_t)(rg * 4 + 1) * G4 + row] = a1;
    X[(size_t)(rg * 4 + 2) * G4 + row] = a2;
    X[(size_t)(rg * 4 + 3) * G4 + row] = a3;
}

// ---------------- whole LSTM in one cooperative kernel ----------------
// grid = 80 blocks (4 batches x 20 chunks of 32 hidden units), 256 threads.
// grid.sync() measured 17us/step (agent-scope fence = cross-XCD L2 traffic) ->
// replaced by a per-batch flag barrier: h published via agent-scope relaxed
// atomic stores (coherence-point, bypasses non-coherent per-XCD L2s), one
// RELEASE fetch_add per block on cnt[b][s]; consumers spin on relaxed agent
// loads and re-read h via agent-scope loads. No L2 flush -> w_hhT slice
// (327KB/block) stays L2-resident. Cooperative launch kept only for the
// co-residency guarantee (confirmed: Occupancy 3.85% = 80x4 waves resident).
__global__ __launch_bounds__(256) void lstm_all(const float* __restrict__ X,
                                                const float* __restrict__ w_hhT,
                                                float* __restrict__ pred,
                                                int* __restrict__ cnt) {
    int b = blockIdx.x / 20;
    int chunk = blockIdx.x % 20;
    __shared__ float hs[HH];
    __shared__ float part[8][128];
    __shared__ float gl[128];
    const int tid = threadIdx.x;
    const int q = tid & 31;           // row-quad 0..31 (4 consecutive gate-rows)
    const int ksl = tid >> 5;         // k-slice 0..7 (80 k each)
    const int g = q >> 3, jq = q & 7;
    const int grow = g * HH + chunk * 32 + jq * 4;   // global gate-row of quad base
    const float4* w4 = (const float4*)w_hhT;         // [k][G4/4]
    const int w4idx0 = grow >> 2;
    const int rowX = (tid >> 5) * HH + chunk * 32 + (tid & 31);  // for tid<128
    float creg = 0.f;                 // c state (threads 0..31)

    for (int s = 0; s < U1; s++) {
        float xv = 0.f;
        if (tid < 128) xv = X[(size_t)(b * U1 + s) * G4 + rowX];   // early issue
        if (s == 0) {
            if (tid < 160) ((float4*)hs)[tid] = (float4){0.f, 0.f, 0.f, 0.f};
        } else {
            if (tid == 0) {
                while (__hip_atomic_load(&cnt[b * U1 + s - 1], __ATOMIC_RELAXED,
                                         __HIP_MEMORY_SCOPE_AGENT) < 20)
                    __builtin_amdgcn_s_sleep(1);
            }
            __syncthreads();
            if (tid < 160) {
                float* hp = pred + (size_t)(b * U1 + (s - 1)) * HH + tid * 4;
                float4 v;
                v.x = __hip_atomic_load(hp + 0, __ATOMIC_RELAXED, __HIP_MEMORY_SCOPE_AGENT);
                v.y = __hip_atomic_load(hp + 1, __ATOMIC_RELAXED, __HIP_MEMORY_SCOPE_AGENT);
                v.z = __hip_atomic_load(hp + 2, __ATOMIC_RELAXED, __HIP_MEMORY_SCOPE_AGENT);
                v.w = __hip_atomic_load(hp + 3, __ATOMIC_RELAXED, __HIP_MEMORY_SCOPE_AGENT);
                ((float4*)hs)[tid] = v;
            }
        }
        __syncthreads();
        float4 acc = {0.f, 0.f, 0.f, 0.f};
        const int k0 = ksl * 80;
#pragma unroll 16
        for (int k = 0; k < 80; k++) {
            float h = hs[k0 + k];
            float4 w = w4[(size_t)(k0 + k) * (G4 / 4) + w4idx0];
            acc.x += h * w.x; acc.y += h * w.y; acc.z += h * w.z; acc.w += h * w.w;
        }
        *(float4*)&part[ksl][q * 4] = acc;
        __syncthreads();
        if (tid < 128) {
            float sum = 0.f;
#pragma unroll
            for (int i = 0; i < 8; i++) sum += part[i][tid];
            gl[tid] = sum + xv;
        }
        __syncthreads();
        if (tid < 32) {
            float iv = sigm(gl[0 * 32 + tid]);
            float fv = sigm(gl[1 * 32 + tid]);
            float gv = tanhf(gl[2 * 32 + tid]);
            float ov = sigm(gl[3 * 32 + tid]);
            creg = fv * creg + iv * gv;
            float h = ov * tanhf(creg);
            __hip_atomic_store(&pred[(size_t)(b * U1 + s) * HH + chunk * 32 + tid], h,
                               __ATOMIC_RELAXED, __HIP_MEMORY_SCOPE_AGENT);
        }
        __syncthreads();              // all h stores issued+drained before flag
        if (tid == 0)
            __hip_atomic_fetch_add(&cnt[b * U1 + s], 1, __ATOMIC_RELEASE,
                                   __HIP_MEMORY_SCOPE_AGENT);
    }
}

// ---------------- f_enc = encT @ enc_w.T + enc_b : [1024][640] ----------------
__global__ __launch_bounds__(256) void fenc_k(const float* __restrict__ encT,
                                              const float* __restrict__ enc_wT,
                                              const float* __restrict__ enc_b,
                                              float* __restrict__ fenc) {
    __shared__ float es[4][ED];
    int r0 = blockIdx.x * 4;   // (b,t) flat
    for (int e = threadIdx.x; e < 4 * ED / 4; e += 256)
        ((float4*)es)[e] = ((const float4*)(encT + (size_t)r0 * ED))[e];
    __syncthreads();
    for (int j = threadIdx.x; j < JJ; j += 256) {
        float bias = enc_b[j];
        float a0 = bias, a1 = bias, a2 = bias, a3 = bias;
#pragma unroll 8
        for (int d = 0; d < ED; d++) {
            float w = enc_wT[(size_t)d * JJ + j];
            a0 += es[0][d] * w;
            a1 += es[1][d] * w;
            a2 += es[2][d] * w;
            a3 += es[3][d] * w;
        }
        fenc[(size_t)(r0 + 0) * JJ + j] = a0;
        fenc[(size_t)(r0 + 1) * JJ + j] = a1;
        fenc[(size_t)(r0 + 2) * JJ + j] = a2;
        fenc[(size_t)(r0 + 3) * JJ + j] = a3;
    }
}

// ---------------- f_pred = pred @ pred_w.T + pred_b : [260][640] ----------------
__global__ __launch_bounds__(256) void fpred_k(const float* __restrict__ pred,
                                               const float* __restrict__ pred_wT,
                                               const float* __restrict__ pred_b,
                                               float* __restrict__ fpred) {
    __shared__ float ps[4][HH];
    int r0 = blockIdx.x * 4;   // (b,u) flat
    for (int e = threadIdx.x; e < 4 * HH / 4; e += 256)
        ((float4*)ps)[e] = ((const float4*)(pred + (size_t)r0 * HH))[e];
    __syncthreads();
    for (int j = threadIdx.x; j < JJ; j += 256) {
        float bias = pred_b[j];
        float a0 = bias, a1 = bias, a2 = bias, a3 = bias;
#pragma unroll 8
        for (int k = 0; k < HH; k++) {
            float w = pred_wT[(size_t)k * JJ + j];
            a0 += ps[0][k] * w;
            a1 += ps[1][k] * w;
            a2 += ps[2][k] * w;
            a3 += ps[3][k] * w;
        }
        fpred[(size_t)(r0 + 0) * JJ + j] = a0;
        fpred[(size_t)(r0 + 1) * JJ + j] = a1;
        fpred[(size_t)(r0 + 2) * JJ + j] = a2;
        fpred[(size_t)(r0 + 3) * JJ + j] = a3;
    }
}

// ---------------- convert fp32 -> bf16 (for out_w), vectorized ----------------
__global__ __launch_bounds__(256) void cvt_bf16_k(const float4* __restrict__ in,
                                                  ushort4* __restrict__ outp, int n4) {
    int i = blockIdx.x * 256 + threadIdx.x;
    if (i >= n4) return;
    float4 v = in[i];
    ushort4 o;
    __hip_bfloat16 h0 = __float2bfloat16(v.x);
    __hip_bfloat16 h1 = __float2bfloat16(v.y);
    __hip_bfloat16 h2 = __float2bfloat16(v.z);
    __hip_bfloat16 h3 = __float2bfloat16(v.w);
    o.x = *(ushort*)&h0; o.y = *(ushort*)&h1;
    o.z = *(ushort*)&h2; o.w = *(ushort*)&h3;
    outp[i] = o;
}

// ---------------- joint GEMM (bf16 MFMA, m97-style, fused A) ----------------
// C[m][v] = sum_k relu(fenc[bt][k]+fpred[b,u][k]) * W[v][k] + out_b[v]
// m = bt*65+u in [0,66560), v in [0,1025). tile 128x128, BK=32, 4 waves.
// A-tile: T14 split staging (global loads issued right after barrier, cvt +
// ds_write after the MFMA cluster); W via global_load_lds(16B).
// grid = dim3(9, 520) with XCD-grouping swizzle (4680 % 8 == 0 -> bijective).
__global__ __launch_bounds__(256) void joint_mfma(const float* __restrict__ fenc,
                                                  const float* __restrict__ fpred,
                                                  const __hip_bfloat16* __restrict__ W,
                                                  const float* __restrict__ out_b,
                                                  float* __restrict__ out) {
    __shared__ __align__(16) short Abuf[2][4096];   // [128 m][32 k] bf16, 64B rows
    __shared__ __align__(16) short Bbuf[2][4096];   // [128 v][32 k] bf16
    const int lin = blockIdx.y * 9 + blockIdx.x;
    const int swz = (lin & 7) * 585 + (lin >> 3);
    const int v0 = (swz % 9) * 128;
    const int row0 = (swz / 9) * 128;
    const int tid = threadIdx.x;
    const int l = tid & 63;
    const int wv = tid >> 6;          // wave 0..3
    const int wr = wv >> 1, wc = wv & 1;

    // ---- W staging (global_load_lds): wave wv covers v-rows [wv*32, wv*32+32)
    const char* Wb = (const char*)W;
    const int brow = v0 + wv * 32 + (l >> 2);
    const int ksegB = (l & 3) * 16;

    // ---- A staging (reg): thread t -> m-row t>>1, k-half t&1 (16 k's)
    const int arow_l = tid >> 1;
    const int kh = tid & 1;
    const int am = row0 + arow_l;
    const int abt = am / 65;
    const int au = am - abt * 65;
    const int ab = abt >> 8;
    const float* feP = fenc + (size_t)abt * JJ + kh * 16;
    const float* fpP = fpred + (size_t)(ab * U1 + au) * JJ + kh * 16;

    f32x4 acc[4][4];
#pragma unroll
    for (int i = 0; i < 4; i++)
#pragma unroll
        for (int j = 0; j < 4; j++) acc[i][j] = (f32x4){0.f, 0.f, 0.f, 0.f};

    auto stageW = [&](int buf, int kc) {
        size_t kb = (size_t)kc * 64;   // 32 bf16 = 64B per v-row chunk
#pragma unroll
        for (int i = 0; i < 2; i++) {
            int vr = brow + i * 16;
            if (vr > 1024) vr = 1024;   // padded n-tile: clamp to a valid row
            const char* g = Wb + (size_t)vr * 1280 + kb + ksegB;
            GLOAD_LDS16(g, &Bbuf[buf][wv * 1024 + i * 512]);
        }
    };
    struct ARegs { float4 e0, e1, e2, e3, p0, p1, p2, p3; };
    auto stageA_load = [&](int kc) -> ARegs {
        const int k0 = kc * 32;
        ARegs r;
        r.e0 = *(const float4*)(feP + k0);
        r.e1 = *(const float4*)(feP + k0 + 4);
        r.e2 = *(const float4*)(feP + k0 + 8);
        r.e3 = *(const float4*)(feP + k0 + 12);
        r.p0 = *(const float4*)(fpP + k0);
        r.p1 = *(const float4*)(fpP + k0 + 4);
        r.p2 = *(const float4*)(fpP + k0 + 8);
        r.p3 = *(const float4*)(fpP + k0 + 12);
        return r;
    };
    auto stageA_store = [&](int buf, const ARegs& r) {
        float v[16] = {
            r.e0.x + r.p0.x, r.e0.y + r.p0.y, r.e0.z + r.p0.z, r.e0.w + r.p0.w,
            r.e1.x + r.p1.x, r.e1.y + r.p1.y, r.e1.z + r.p1.z, r.e1.w + r.p1.w,
            r.e2.x + r.p2.x, r.e2.y + r.p2.y, r.e2.z + r.p2.z, r.e2.w + r.p2.w,
            r.e3.x + r.p3.x, r.e3.y + r.p3.y, r.e3.z + r.p3.z, r.e3.w + r.p3.w};
        union { ushort h[16]; uint4 q[2]; } pk;
#pragma unroll
        for (int i = 0; i < 16; i++) {
            __hip_bfloat16 hb = __float2bfloat16(fmaxf(v[i], 0.f));
            pk.h[i] = *(ushort*)&hb;
        }
        *(uint4*)&Abuf[buf][arow_l * 32 + kh * 16] = pk.q[0];
        *(uint4*)&Abuf[buf][arow_l * 32 + kh * 16 + 8] = pk.q[1];
    };

    stageW(0, 0);
    stageA_store(0, stageA_load(0));
    int cur = 0;
    const int lr = l & 15, lg = l >> 4;
    for (int kc = 0; kc < 20; kc++) {
        __syncthreads();               // drains vmcnt (gload_lds) + lgkmcnt (ds_write)
        ARegs ar;
        if (kc < 19) {
            stageW(cur ^ 1, kc + 1);
            ar = stageA_load(kc + 1);  // issue early: latency hides under MFMAs
        }
        bf16x8 af[4], bfr[4];
#pragma unroll
        for (int mf = 0; mf < 4; mf++)
            af[mf] = *(const bf16x8*)&Abuf[cur][(wr * 64 + mf * 16 + lr) * 32 + lg * 8];
#pragma unroll
        for (int nf = 0; nf < 4; nf++)
            bfr[nf] = *(const bf16x8*)&Bbuf[cur][(wc * 64 + nf * 16 + lr) * 32 + lg * 8];
#pragma unroll
        for (int mf = 0; mf < 4; mf++)
#pragma unroll
            for (int nf = 0; nf < 4; nf++)
                acc[mf][nf] = __builtin_amdgcn_mfma_f32_16x16x32_bf16(af[mf], bfr[nf], acc[mf][nf], 0, 0, 0);
        if (kc < 19) stageA_store(cur ^ 1, ar);   // cvt+ds_write after MFMA cluster
        cur ^= 1;
    }

    // epilogue: C/D layout col=lane&15, row=(lane>>4)*4+reg
#pragma unroll
    for (int nf = 0; nf < 4; nf++) {
        int vcol = v0 + wc * 64 + nf * 16 + lr;
        if (vcol < V1) {
            float bias = out_b[vcol];
#pragma unroll
            for (int mf = 0; mf < 4; mf++) {
#pragma unroll
                for (int rg = 0; rg < 4; rg++) {
                    int m = row0 + wr * 64 + mf * 16 + lg * 4 + rg;
                    out[(size_t)m * V1 + vcol] = acc[mf][nf][rg] + bias;
                }
            }
        }
    }
}

extern "C" void kernel_launch(void* const* d_in, const int* in_sizes, int n_in,
                              void* d_out, int out_size, void* d_ws, size_t ws_size,
                              hipStream_t stream) {
    const float* enc = (const float*)d_in[0];
    const int* targets = (const int*)d_in[2];
    const float* embed = (const float*)d_in[4];
    const float* w_ih = (const float*)d_in[5];
    const float* w_hh = (const float*)d_in[6];
    const float* b_ih = (const float*)d_in[7];
    const float* b_hh = (const float*)d_in[8];
    const float* enc_w = (const float*)d_in[9];
    const float* enc_b = (const float*)d_in[10];
    const float* pred_w = (const float*)d_in[11];
    const float* pred_b = (const float*)d_in[12];
    const float* out_w = (const float*)d_in[13];
    const float* out_b = (const float*)d_in[14];
    float* out = (float*)d_out;

    float* w0 = (float*)d_ws;
    size_t o = 0;
    float* w_ihT = w0 + o; o += (size_t)640 * 2560;   // [k][gate-row]
    float* w_hhT = w0 + o; o += (size_t)640 * 2560;
    float* enc_wT = w0 + o; o += (size_t)512 * 640;   // [d][j]
    float* pred_wT = w0 + o; o += (size_t)640 * 640;  // [k][j]
    float* encT = w0 + o; o += (size_t)BB * TT * ED;  // [b][t][d]
    float* y = w0 + o; o += (size_t)BB * U1 * HH;
    float* X = w0 + o; o += (size_t)BB * U1 * G4;
    float* pred = w0 + o; o += (size_t)BB * U1 * HH;
    float* fenc = w0 + o; o += (size_t)BB * TT * JJ;
    float* fpred = w0 + o; o += (size_t)BB * U1 * JJ;
    __hip_bfloat16* W_bf = (__hip_bfloat16*)(w0 + o); o += (size_t)V1 * JJ / 2 + 8;
    int* cnt = (int*)(w0 + o); o += BB * U1;          // per-(b,step) barrier counters

    auto TP = [&](const float* in, float* outp, int R, int C) {
        transpose_tiled<<<dim3(C / 32, R / 32), 256, 0, stream>>>(in, outp, R, C);
    };
    TP(w_ih, w_ihT, 2560, 640);
    TP(w_hh, w_hhT, 2560, 640);
    TP(enc_w, enc_wT, 640, 512);
    TP(pred_w, pred_wT, 640, 640);
    for (int b = 0; b < BB; b++)
        TP(enc + (size_t)b * ED * TT, encT + (size_t)b * TT * ED, ED, TT);

    zero_cnt<<<2, 256, 0, stream>>>(cnt);
    build_y<<<(BB * U1 * HH + 255) / 256, 256, 0, stream>>>(targets, embed, y);
    gemm_x<<<650, 256, 0, stream>>>(y, w_ihT, b_ih, b_hh, X);

    {
        void* kargs[] = {(void*)&X, (void*)&w_hhT, (void*)&pred, (void*)&cnt};
        hipLaunchCooperativeKernel((void*)lstm_all, dim3(80), dim3(256), kargs, 0, stream);
    }

    fenc_k<<<BB * TT / 4, 256, 0, stream>>>(encT, enc_wT, enc_b, fenc);
    fpred_k<<<BB * U1 / 4, 256, 0, stream>>>(pred, pred_wT, pred_b, fpred);
    cvt_bf16_k<<<(V1 * JJ / 4 + 255) / 256, 256, 0, stream>>>((const float4*)out_w,
                                                              (ushort4*)W_bf, V1 * JJ / 4);
    joint_mfma<<<dim3(9, 520), 256, 0, stream>>>(fenc, fpred, W_bf, out_b, out);
}